// Round 9
// baseline (200.989 us; speedup 1.0000x reference)
//
#include <hip/hip_runtime.h>
#include <stdint.h>

#define EPSF 1e-5f
#define LOG2E 1.4426950408889634f

typedef float f32x2 __attribute__((ext_vector_type(2)));
typedef float f32x4 __attribute__((ext_vector_type(4)));

__device__ __forceinline__ float bflo(uint32_t u){ union{uint32_t u;float f;}c; c.u=u<<16; return c.f; }
__device__ __forceinline__ float bfhi(uint32_t u){ union{uint32_t u;float f;}c; c.u=u&0xffff0000u; return c.f; }
// raw high-half: value == bf16_hi * (1+delta), |delta| <= 2^-7
__device__ __forceinline__ float bfhiraw(uint32_t u){ union{uint32_t u;float f;}c; c.u=u; return c.f; }
__device__ __forceinline__ uint32_t f2bf(float f){ union{float f;uint32_t u;}c; c.f=f; uint32_t u=c.u; return (u + 0x7fffu + ((u>>16)&1u)) >> 16; }
__device__ __forceinline__ uint32_t pk2(float a, float b){ return f2bf(a) | (f2bf(b)<<16); }

// ---- guaranteed VOP3P packed f32 (gfx950) ----
__device__ __forceinline__ f32x2 pk_add(f32x2 a, f32x2 b){
  f32x2 d; asm("v_pk_add_f32 %0, %1, %2" : "=v"(d) : "v"(a), "v"(b)); return d;
}
__device__ __forceinline__ f32x2 pk_mul(f32x2 a, f32x2 b){
  f32x2 d; asm("v_pk_mul_f32 %0, %1, %2" : "=v"(d) : "v"(a), "v"(b)); return d;
}
__device__ __forceinline__ f32x2 pk_fma(f32x2 a, f32x2 b, f32x2 c){
  f32x2 d; asm("v_pk_fma_f32 %0, %1, %2, %3" : "=v"(d) : "v"(a), "v"(b), "v"(c)); return d;
}
__device__ __forceinline__ f32x2 up2(uint32_t u){
  f32x2 r; r.x = bflo(u); r.y = bfhiraw(u); return r;
}

// ---------------- rel_enc packing (both tables, one launch, bf16) ----------------
__global__ void k_relpack(const float* __restrict__ relH, const float* __restrict__ relW,
                          uint4* __restrict__ rqkH, uint4* __restrict__ rveH,
                          uint4* __restrict__ rqkW, uint4* __restrict__ rveW) {
  int NJ = blockIdx.x ? 255 : 511;
  const float* rel = blockIdx.x ? relW : relH;
  uint4* rqk = blockIdx.x ? rqkW : rqkH;
  uint4* rve = blockIdx.x ? rveW : rveH;
  int j = threadIdx.x;
  if (j >= NJ) return;
  const float* q = rel;
  const float* k = rel + 4*NJ;
  const float* v = rel + 8*NJ;
  int jr = NJ-1-j;
  uint4 a;
  a.x = pk2(q[0*NJ+j], q[1*NJ+j]);
  a.y = pk2(q[2*NJ+j], q[3*NJ+j]);
  a.z = pk2(k[0*NJ+jr], k[1*NJ+jr]);
  a.w = pk2(k[2*NJ+jr], k[3*NJ+jr]);
  rqk[j] = a;
  uint4 b;
  b.x = pk2(v[0*NJ+j], v[1*NJ+j]);
  b.y = pk2(v[2*NJ+j], v[3*NJ+j]);
  b.z = pk2(v[4*NJ+j], v[5*NJ+j]);
  b.w = pk2(v[6*NJ+j], v[7*NJ+j]);
  rve[j] = b;
}

// ---------------- conv1 + bn + relu : NCHW in -> NHWC out ----------------
__global__ __launch_bounds__(256)
void k_conv1(const float* __restrict__ in, const float* __restrict__ w,
             const float* __restrict__ bn, float* __restrict__ out) {
  __shared__ float L[64*65];
  int tid = threadIdx.x;
  int p0 = blockIdx.x * 64;
  int lane = tid & 63;
  int wvs = __builtin_amdgcn_readfirstlane(tid >> 6);
  #pragma unroll
  for (int rr = 0; rr < 16; ++rr) {
    int c = wvs*16 + rr;
    L[lane*65 + c] = in[(size_t)c*32768 + p0 + lane];
  }
  __syncthreads();
  f32x2 xv2[32];
  #pragma unroll
  for (int c2 = 0; c2 < 32; ++c2) {
    xv2[c2].x = L[lane*65 + 2*c2];
    xv2[c2].y = L[lane*65 + 2*c2 + 1];
  }
  float val[16];
  #pragma unroll
  for (int r = 0; r < 16; ++r) {
    int o = wvs*16 + r;
    const f32x2* wr = (const f32x2*)(w + o*64);
    f32x2 a2 = {0.f, 0.f};
    #pragma unroll
    for (int c2 = 0; c2 < 32; ++c2) a2 = wr[c2]*xv2[c2] + a2;
    float acc = a2.x + a2.y;
    float s = bn[o] * rsqrtf(bn[192+o] + EPSF);
    val[r] = fmaxf(fmaf(acc, s, fmaf(-bn[128+o], s, bn[64+o])), 0.f);
  }
  __syncthreads();
  #pragma unroll
  for (int r = 0; r < 16; ++r) L[lane*65 + wvs*16 + r] = val[r];
  __syncthreads();
  float4* dst = (float4*)(out + (size_t)p0*64);
  #pragma unroll
  for (int k = 0; k < 4; ++k) {
    int f4 = tid + k*256;
    int f = f4*4; int p = f >> 6, o = f & 63;
    float4 v;
    v.x = L[p*65+o]; v.y = L[p*65+o+1]; v.z = L[p*65+o+2]; v.w = L[p*65+o+3];
    dst[f4] = v;
  }
}

// ---------------- kqv projection + bn -> bf16 K/V + f32 Q ----------------
template<int LEN, int RS, int CS>
__global__ __launch_bounds__(512)
void k_kqv(const float* __restrict__ in, const float* __restrict__ w,
           const float* __restrict__ bn, uint4* __restrict__ kvV,
           uint2* __restrict__ kvK, float* __restrict__ qb) {
  __shared__ float L[64*65];
  int tid = threadIdx.x;
  int n = blockIdx.x;
  int y0 = blockIdx.y * 64;
  #pragma unroll
  for (int rr = 0; rr < 8; ++rr) {
    int idx = tid + rr*512;
    int yy = idx >> 6, c = idx & 63;
    L[yy*65 + c] = in[((size_t)(y0+yy)*RS + (size_t)n*CS)*64 + c];
  }
  __syncthreads();
  int hd = __builtin_amdgcn_readfirstlane(tid >> 6);
  int yy = tid & 63;
  f32x2 xv2[32];
  #pragma unroll
  for (int c2 = 0; c2 < 32; ++c2) {
    xv2[c2].x = L[yy*65 + 2*c2];
    xv2[c2].y = L[yy*65 + 2*c2 + 1];
  }
  float val[16];
  #pragma unroll
  for (int r = 0; r < 16; ++r) {
    int o = hd*16 + r;
    const f32x2* wr = (const f32x2*)(w + o*64);
    f32x2 a2 = {0.f, 0.f};
    #pragma unroll
    for (int c2 = 0; c2 < 32; ++c2) a2 = wr[c2]*xv2[c2] + a2;
    float acc = a2.x + a2.y;
    float s = bn[o] * rsqrtf(bn[384+o] + EPSF);
    val[r] = fmaf(acc, s, fmaf(-bn[256+o], s, bn[128+o]));
  }
  size_t base = ((size_t)n*8 + hd)*LEN + (y0 + yy);
  kvK[base] = make_uint2(pk2(val[0],val[1]), pk2(val[2],val[3]));
  kvV[base] = make_uint4(pk2(val[8],val[9]),  pk2(val[10],val[11]),
                         pk2(val[12],val[13]), pk2(val[14],val[15]));
  float4 qq; qq.x = val[4]; qq.y = val[5]; qq.z = val[6]; qq.w = val[7];
  *(float4*)(qb + base*4) = qq;
}

// ---------------- axial attention core (v9: x-split, G=8, staged merge) ----------------
struct E4 { f32x2 qe0, qe1, ke0, ke1; };   // unpacked qe'/ke'' entry
struct V4 { f32x2 a, b, c, d; };           // unpacked ve entry

__device__ __forceinline__ E4 upQK(uint4 u){
  E4 r; r.qe0 = up2(u.x); r.qe1 = up2(u.y); r.ke0 = up2(u.z); r.ke1 = up2(u.w); return r;
}
__device__ __forceinline__ V4 upVE(uint4 u){
  V4 r; r.a = up2(u.x); r.b = up2(u.y); r.c = up2(u.z); r.d = up2(u.w); return r;
}
// logit2 = kt.(q + ke'') + q.qe'
__device__ __forceinline__ float pairA(f32x2 q01, f32x2 q23, const E4& e,
                                       f32x2 ktlo, f32x2 kthi) {
  f32x2 t0 = pk_add(q01, e.ke0);
  f32x2 t1 = pk_add(q23, e.ke1);
  f32x2 s  = pk_mul(t0, ktlo);
  s = pk_fma(t1, kthi, s);
  s = pk_fma(q01, e.qe0, s);
  s = pk_fma(q23, e.qe1, s);
  return s.x + s.y;
}
__device__ __forceinline__ void pairB(float ex, const V4& ve,
                                      f32x2 va01, f32x2 va23, f32x2 vb01, f32x2 vb23,
                                      f32x2* A, float& ss) {
  ss += ex;
  f32x2 e2; e2.x = ex; e2.y = ex;
  A[0] = pk_fma(e2, pk_add(va01, ve.a), A[0]);
  A[1] = pk_fma(e2, pk_add(va23, ve.b), A[1]);
  A[2] = pk_fma(e2, pk_add(vb01, ve.c), A[2]);
  A[3] = pk_fma(e2, pk_add(vb23, ve.d), A[3]);
}

// LEN = seq length; XR = x's per block (x-split when XR<LEN); G = y-groups.
// T = XR/4*G threads. thread (g, tl): x = xh*XR + 4*tl + i, y in [g*YR, (g+1)*YR).
template<int LEN, int XR, int G, bool RELUO, int XS, int NS>
__global__ __launch_bounds__(XR/4*G, 2)
void k_attn6(const uint4* __restrict__ kvV, const uint2* __restrict__ kvK,
             const float* __restrict__ qb, const uint4* __restrict__ rqk,
             const uint4* __restrict__ rve, const float* __restrict__ lbn,
             float* __restrict__ out) {
  constexpr int NJ = 2*LEN-1;
  constexpr int NJ4 = (NJ+1)/4;
  constexpr int XT = XR/4;
  constexpr int T = XT*G;
  constexpr int YR = LEN/G;
  constexpr int NXB = LEN/XR;
  constexpr size_t S1 = (size_t)LEN*48 + (size_t)NJ4*4*16*2;
  constexpr size_t S2 = (size_t)XR*40;            // staged merge buffer
  constexpr size_t PS = S1 > S2 ? S1 : S2;
  int bx = blockIdx.x;
  int xh = bx % NXB;
  int nh = bx / NXB;
  int n  = nh >> 3;
  int hd = nh & 7;
  int t  = threadIdx.x;

  __shared__ __align__(16) char pool[PS];
  f32x4* sKt = (f32x4*)(pool);                              // [LEN] A0L*k
  f32x4* sVa = (f32x4*)(pool + (size_t)LEN*16);             // [LEN] v0..3
  f32x4* sVb = (f32x4*)(pool + (size_t)LEN*32);             // [LEN] v4..7
  uint4* tQK = (uint4*)(pool + (size_t)LEN*48);             // [4][NJ4]
  uint4* tVE = (uint4*)(pool + (size_t)LEN*48 + (size_t)NJ4*64); // [4][NJ4]

  float A0L, A1L, A2L;
  {
    int c0 = hd, c1 = 8+hd, c2 = 16+hd;
    A0L = lbn[c0]*rsqrtf(lbn[72+c0]+EPSF)*LOG2E;
    A1L = lbn[c1]*rsqrtf(lbn[72+c1]+EPSF)*LOG2E;
    A2L = lbn[c2]*rsqrtf(lbn[72+c2]+EPSF)*LOG2E;
  }
  float A0g = (fabsf(A0L) > 1e-25f) ? A0L : copysignf(1e-25f, A0L);
  float ratio = A2L / A0g;

  size_t kvbase = ((size_t)n*8 + hd)*LEN;
  for (int i = t; i < LEN; i += T) {
    uint2 kk = kvK[kvbase + i];
    uint4 vv = kvV[kvbase + i];
    f32x4 kt; kt.x=bflo(kk.x)*A0g; kt.y=bfhi(kk.x)*A0g; kt.z=bflo(kk.y)*A0g; kt.w=bfhi(kk.y)*A0g;
    sKt[i] = kt;
    f32x4 va; va.x=bflo(vv.x); va.y=bfhi(vv.x); va.z=bflo(vv.y); va.w=bfhi(vv.y);
    sVa[i] = va;
    f32x4 vb; vb.x=bflo(vv.z); vb.y=bfhi(vv.z); vb.z=bflo(vv.w); vb.w=bfhi(vv.w);
    sVb[i] = vb;
  }
  for (int j = t; j < NJ; j += T) {
    uint4 a = rqk[j];
    uint4 sq;
    sq.x = pk2(bflo(a.x)*A1L,   bfhi(a.x)*A1L);
    sq.y = pk2(bflo(a.y)*A1L,   bfhi(a.y)*A1L);
    sq.z = pk2(bflo(a.z)*ratio, bfhi(a.z)*ratio);
    sq.w = pk2(bflo(a.w)*ratio, bfhi(a.w)*ratio);
    int r = j & 3, mm = j >> 2;
    tQK[r*NJ4 + mm] = sq;
    tVE[r*NJ4 + mm] = rve[j];
  }

  int g  = t / XT;
  int tl = t % XT;
  int y0 = g * YR;
  int x0 = xh*XR + 4*tl;        // global x base

  f32x2 q01[4], q23[4];
  #pragma unroll
  for (int i = 0; i < 4; ++i) {
    f32x4 qq = *(const f32x4*)(qb + (kvbase + x0 + i)*4);
    q01[i].x = qq.x; q01[i].y = qq.y;
    q23[i].x = qq.z; q23[i].y = qq.w;
  }

  float m[4], ss[4];
  f32x2 acc[4][4];
  #pragma unroll
  for (int i=0;i<4;++i){ m[i]=-3.0e38f; ss[i]=0.f;
    #pragma unroll
    for(int d=0;d<4;++d){ acc[i][d].x=0.f; acc[i][d].y=0.f; } }

  __syncthreads();

  // window prologue: (y0 + LEN-1) & 3 == 3 always (y0, x0 mult of 4)
  int mi = ((y0 + LEN-1) >> 2) - (x0 >> 2);
  E4 Wq0 = upQK(tQK[0*NJ4 + mi]), Wq1 = upQK(tQK[1*NJ4 + mi]), Wq2 = upQK(tQK[2*NJ4 + mi]);
  V4 Wv0 = upVE(tVE[0*NJ4 + mi]), Wv1 = upVE(tVE[1*NJ4 + mi]), Wv2 = upVE(tVE[2*NJ4 + mi]);

  for (int cc = 0; cc < YR/4; ++cc) {
    int yb = y0 + 4*cc;
    int ma = mi + cc;
    int mb = ma + 1;
    float lr[4][4];
    // ---- pass A (parities 3,0,1,2) ----
    E4 E3 = upQK(tQK[3*NJ4 + ma]);
    { f32x4 kt = sKt[yb]; f32x2 kl = kt.lo, kh = kt.hi;
      lr[0][0]=pairA(q01[0],q23[0],E3, kl,kh); lr[1][0]=pairA(q01[1],q23[1],Wq2,kl,kh);
      lr[2][0]=pairA(q01[2],q23[2],Wq1,kl,kh); lr[3][0]=pairA(q01[3],q23[3],Wq0,kl,kh); }
    E4 E0 = upQK(tQK[0*NJ4 + mb]);
    { f32x4 kt = sKt[yb+1]; f32x2 kl = kt.lo, kh = kt.hi;
      lr[0][1]=pairA(q01[0],q23[0],E0, kl,kh); lr[1][1]=pairA(q01[1],q23[1],E3, kl,kh);
      lr[2][1]=pairA(q01[2],q23[2],Wq2,kl,kh); lr[3][1]=pairA(q01[3],q23[3],Wq1,kl,kh); }
    E4 E1 = upQK(tQK[1*NJ4 + mb]);
    { f32x4 kt = sKt[yb+2]; f32x2 kl = kt.lo, kh = kt.hi;
      lr[0][2]=pairA(q01[0],q23[0],E1, kl,kh); lr[1][2]=pairA(q01[1],q23[1],E0, kl,kh);
      lr[2][2]=pairA(q01[2],q23[2],E3, kl,kh); lr[3][2]=pairA(q01[3],q23[3],Wq2,kl,kh); }
    E4 E2 = upQK(tQK[2*NJ4 + mb]);
    { f32x4 kt = sKt[yb+3]; f32x2 kl = kt.lo, kh = kt.hi;
      lr[0][3]=pairA(q01[0],q23[0],E2, kl,kh); lr[1][3]=pairA(q01[1],q23[1],E1, kl,kh);
      lr[2][3]=pairA(q01[2],q23[2],E0, kl,kh); lr[3][3]=pairA(q01[3],q23[3],E3, kl,kh); }
    Wq0 = E0; Wq1 = E1; Wq2 = E2;
    // ---- branchless chunk rescale (pk_mul) ----
    #pragma unroll
    for (int i = 0; i < 4; ++i) {
      float cm = fmaxf(fmaxf(lr[i][0], lr[i][1]), fmaxf(lr[i][2], lr[i][3]));
      float mn = fmaxf(m[i], cm);
      float sc = __builtin_amdgcn_exp2f(m[i] - mn);
      m[i] = mn; ss[i] *= sc;
      f32x2 sc2; sc2.x = sc; sc2.y = sc;
      #pragma unroll
      for (int d = 0; d < 4; ++d) acc[i][d] = pk_mul(acc[i][d], sc2);
    }
    // ---- pass B (same window schedule) ----
    V4 F3 = upVE(tVE[3*NJ4 + ma]);
    { f32x4 va = sVa[yb], vb = sVb[yb];
      pairB(__builtin_amdgcn_exp2f(lr[0][0]-m[0]), F3,  va.lo,va.hi,vb.lo,vb.hi, acc[0], ss[0]);
      pairB(__builtin_amdgcn_exp2f(lr[1][0]-m[1]), Wv2, va.lo,va.hi,vb.lo,vb.hi, acc[1], ss[1]);
      pairB(__builtin_amdgcn_exp2f(lr[2][0]-m[2]), Wv1, va.lo,va.hi,vb.lo,vb.hi, acc[2], ss[2]);
      pairB(__builtin_amdgcn_exp2f(lr[3][0]-m[3]), Wv0, va.lo,va.hi,vb.lo,vb.hi, acc[3], ss[3]); }
    V4 F0 = upVE(tVE[0*NJ4 + mb]);
    { f32x4 va = sVa[yb+1], vb = sVb[yb+1];
      pairB(__builtin_amdgcn_exp2f(lr[0][1]-m[0]), F0,  va.lo,va.hi,vb.lo,vb.hi, acc[0], ss[0]);
      pairB(__builtin_amdgcn_exp2f(lr[1][1]-m[1]), F3,  va.lo,va.hi,vb.lo,vb.hi, acc[1], ss[1]);
      pairB(__builtin_amdgcn_exp2f(lr[2][1]-m[2]), Wv2, va.lo,va.hi,vb.lo,vb.hi, acc[2], ss[2]);
      pairB(__builtin_amdgcn_exp2f(lr[3][1]-m[3]), Wv1, va.lo,va.hi,vb.lo,vb.hi, acc[3], ss[3]); }
    V4 F1 = upVE(tVE[1*NJ4 + mb]);
    { f32x4 va = sVa[yb+2], vb = sVb[yb+2];
      pairB(__builtin_amdgcn_exp2f(lr[0][2]-m[0]), F1,  va.lo,va.hi,vb.lo,vb.hi, acc[0], ss[0]);
      pairB(__builtin_amdgcn_exp2f(lr[1][2]-m[1]), F0,  va.lo,va.hi,vb.lo,vb.hi, acc[1], ss[1]);
      pairB(__builtin_amdgcn_exp2f(lr[2][2]-m[2]), F3,  va.lo,va.hi,vb.lo,vb.hi, acc[2], ss[2]);
      pairB(__builtin_amdgcn_exp2f(lr[3][2]-m[3]), Wv2, va.lo,va.hi,vb.lo,vb.hi, acc[3], ss[3]); }
    V4 F2 = upVE(tVE[2*NJ4 + mb]);
    { f32x4 va = sVa[yb+3], vb = sVb[yb+3];
      pairB(__builtin_amdgcn_exp2f(lr[0][3]-m[0]), F2,  va.lo,va.hi,vb.lo,vb.hi, acc[0], ss[0]);
      pairB(__builtin_amdgcn_exp2f(lr[1][3]-m[1]), F1,  va.lo,va.hi,vb.lo,vb.hi, acc[1], ss[1]);
      pairB(__builtin_amdgcn_exp2f(lr[2][3]-m[2]), F0,  va.lo,va.hi,vb.lo,vb.hi, acc[2], ss[2]);
      pairB(__builtin_amdgcn_exp2f(lr[3][3]-m[3]), F3,  va.lo,va.hi,vb.lo,vb.hi, acc[3], ss[3]); }
    Wv0 = F0; Wv1 = F1; Wv2 = F2;
  }

  // ---- staged sequential G-way merge (LDS = XR*40 bytes) ----
  __syncthreads();
  float4* M0 = (float4*)(pool);                     // [XR]
  float4* M1 = (float4*)(pool + (size_t)XR*16);     // [XR]
  float2* MS = (float2*)(pool + (size_t)XR*32);     // [XR]
  int xl = 4*tl;
  for (int gg = 1; gg < G; ++gg) {
    if (g == gg) {
      #pragma unroll
      for (int i = 0; i < 4; ++i) {
        M0[xl+i] = make_float4(acc[i][0].x,acc[i][0].y,acc[i][1].x,acc[i][1].y);
        M1[xl+i] = make_float4(acc[i][2].x,acc[i][2].y,acc[i][3].x,acc[i][3].y);
        MS[xl+i] = make_float2(m[i], ss[i]);
      }
    }
    __syncthreads();
    if (g == 0) {
      #pragma unroll
      for (int i = 0; i < 4; ++i) {
        float2 os = MS[xl+i];
        float M = fmaxf(m[i], os.x);
        float w0 = __builtin_amdgcn_exp2f(m[i] - M);
        float wg = __builtin_amdgcn_exp2f(os.x - M);
        m[i] = M;
        ss[i] = ss[i]*w0 + os.y*wg;
        float4 a0 = M0[xl+i];
        float4 a1 = M1[xl+i];
        f32x2 w02; w02.x=w0; w02.y=w0;
        f32x2 wg2; wg2.x=wg; wg2.y=wg;
        f32x2 b0; b0.x=a0.x; b0.y=a0.y;
        f32x2 b1; b1.x=a0.z; b1.y=a0.w;
        f32x2 b2; b2.x=a1.x; b2.y=a1.y;
        f32x2 b3; b3.x=a1.z; b3.y=a1.w;
        acc[i][0] = pk_fma(acc[i][0], w02, pk_mul(b0, wg2));
        acc[i][1] = pk_fma(acc[i][1], w02, pk_mul(b1, wg2));
        acc[i][2] = pk_fma(acc[i][2], w02, pk_mul(b2, wg2));
        acc[i][3] = pk_fma(acc[i][3], w02, pk_mul(b3, wg2));
      }
    }
    __syncthreads();
  }
  if (g == 0) {
    #pragma unroll
    for (int i = 0; i < 4; ++i) {
      float inv = 1.0f / ss[i];
      float* dst = out + ((size_t)(x0+i)*XS + (size_t)n*NS)*64 + hd*8;
      float4 lo, hi;
      lo.x = acc[i][0].x*inv; lo.y = acc[i][0].y*inv;
      lo.z = acc[i][1].x*inv; lo.w = acc[i][1].y*inv;
      hi.x = acc[i][2].x*inv; hi.y = acc[i][2].y*inv;
      hi.z = acc[i][3].x*inv; hi.w = acc[i][3].y*inv;
      if (RELUO) {
        lo.x=fmaxf(lo.x,0.f); lo.y=fmaxf(lo.y,0.f); lo.z=fmaxf(lo.z,0.f); lo.w=fmaxf(lo.w,0.f);
        hi.x=fmaxf(hi.x,0.f); hi.y=fmaxf(hi.y,0.f); hi.z=fmaxf(hi.z,0.f); hi.w=fmaxf(hi.w,0.f);
      }
      *(float4*)dst = lo;
      *((float4*)dst + 1) = hi;
    }
  }
}

// ---------------- conv3 + bn + residual + relu : NHWC in -> NCHW out ----------------
__global__ __launch_bounds__(256)
void k_conv3(const float* __restrict__ in, const float* __restrict__ w,
             const float* __restrict__ bn, const float* __restrict__ resid,
             float* __restrict__ out) {
  __shared__ float L[64*65];
  int tid = threadIdx.x;
  int p0 = blockIdx.x * 64;
  const float4* src = (const float4*)(in + (size_t)p0*64);
  #pragma unroll
  for (int k = 0; k < 4; ++k) {
    int f4 = tid + k*256;
    float4 v = src[f4];
    int f = f4*4; int p = f >> 6, o = f & 63;
    L[p*65+o] = v.x; L[p*65+o+1] = v.y; L[p*65+o+2] = v.z; L[p*65+o+3] = v.w;
  }
  __syncthreads();
  int lane = tid & 63;
  int wvs = __builtin_amdgcn_readfirstlane(tid >> 6);
  f32x2 xv2[32];
  #pragma unroll
  for (int c2 = 0; c2 < 32; ++c2) {
    xv2[c2].x = L[lane*65 + 2*c2];
    xv2[c2].y = L[lane*65 + 2*c2 + 1];
  }
  #pragma unroll
  for (int r = 0; r < 16; ++r) {
    int o = wvs*16 + r;
    const f32x2* wr = (const f32x2*)(w + o*64);
    f32x2 a2 = {0.f, 0.f};
    #pragma unroll
    for (int c2 = 0; c2 < 32; ++c2) a2 = wr[c2]*xv2[c2] + a2;
    float acc = a2.x + a2.y;
    float s = bn[o] * rsqrtf(bn[192+o] + EPSF);
    float val = fmaf(acc, s, fmaf(-bn[128+o], s, bn[64+o]));
    size_t idx = (size_t)o*32768 + p0 + lane;
    out[idx] = fmaxf(val + resid[idx], 0.f);
  }
}

extern "C" void kernel_launch(void* const* d_in, const int* in_sizes, int n_in,
                              void* d_out, int out_size, void* d_ws, size_t ws_size,
                              hipStream_t stream) {
  const float* x         = (const float*)d_in[0];
  const float* conv1_w   = (const float*)d_in[1];
  const float* bn1       = (const float*)d_in[2];
  const float* kqv_w_h   = (const float*)d_in[3];
  const float* kqv_bn_h  = (const float*)d_in[4];
  const float* lbn_h     = (const float*)d_in[5];
  const float* rel_h     = (const float*)d_in[6];
  const float* kqv_w_w   = (const float*)d_in[7];
  const float* kqv_bn_w  = (const float*)d_in[8];
  const float* lbn_w     = (const float*)d_in[9];
  const float* rel_w     = (const float*)d_in[10];
  const float* conv3_w   = (const float*)d_in[11];
  const float* bn3       = (const float*)d_in[12];
  float* outp = (float*)d_out;
  char* ws = (char*)d_ws;

  float* A    = (float*)(ws);                    // 8 MiB
  uint4* kvV  = (uint4*)(ws + 8388608);          // 4 MiB
  uint2* kvK  = (uint2*)(ws + 12582912);         // 2 MiB
  float* qb   = (float*)(ws + 14680064);         // 4 MiB (f32 q)
  uint4* rqkH = (uint4*)(ws + 18874368);
  uint4* rveH = (uint4*)(ws + 18882560);
  uint4* rqkW = (uint4*)(ws + 18890752);
  uint4* rveW = (uint4*)(ws + 18894848);

  k_relpack<<<2, 512, 0, stream>>>(rel_h, rel_w, rqkH, rveH, rqkW, rveW);

  // conv1 + bn1 + relu : x NCHW -> A NHWC
  k_conv1<<<512, 256, 0, stream>>>(x, conv1_w, bn1, A);

  // axial-H: n = w (128), seq = h (256); x-split 2, G=8 -> 2048 blocks x 256 thr
  k_kqv<256,128,1><<<dim3(128,4), 512, 0, stream>>>(A, kqv_w_h, kqv_bn_h, kvV, kvK, qb);
  k_attn6<256,128,8,false,128,1><<<2048, 256, 0, stream>>>(kvV, kvK, qb, rqkH, rveH, lbn_h, A);

  // axial-W: n = h (256), seq = w (128); G=8 -> 2048 blocks x 256 thr; relu fused
  k_kqv<128,1,128><<<dim3(256,2), 512, 0, stream>>>(A, kqv_w_w, kqv_bn_w, kvV, kvK, qb);
  k_attn6<128,128,8,true,1,128><<<2048, 256, 0, stream>>>(kvV, kvK, qb, rqkW, rveW, lbn_w, A);

  // conv3 + bn3 + residual + relu : A NHWC -> out NCHW
  k_conv3<<<512, 256, 0, stream>>>(A, conv3_w, bn3, x, outp);
}

// Round 10
// 177.353 us; speedup vs baseline: 1.1333x; 1.1333x over previous
//
#include <hip/hip_runtime.h>
#include <stdint.h>

#define EPSF 1e-5f
#define LOG2E 1.4426950408889634f

typedef float f32x2 __attribute__((ext_vector_type(2)));
typedef float f32x4 __attribute__((ext_vector_type(4)));

__device__ __forceinline__ float bflo(uint32_t u){ union{uint32_t u;float f;}c; c.u=u<<16; return c.f; }
__device__ __forceinline__ float bfhi(uint32_t u){ union{uint32_t u;float f;}c; c.u=u&0xffff0000u; return c.f; }
// raw high-half: value == bf16_hi * (1+delta), |delta| <= 2^-7
__device__ __forceinline__ float bfhiraw(uint32_t u){ union{uint32_t u;float f;}c; c.u=u; return c.f; }
__device__ __forceinline__ uint32_t f2bf(float f){ union{float f;uint32_t u;}c; c.f=f; uint32_t u=c.u; return (u + 0x7fffu + ((u>>16)&1u)) >> 16; }
__device__ __forceinline__ uint32_t pk2(float a, float b){ return f2bf(a) | (f2bf(b)<<16); }

// ---- guaranteed VOP3P packed f32 (gfx950) ----
__device__ __forceinline__ f32x2 pk_add(f32x2 a, f32x2 b){
  f32x2 d; asm("v_pk_add_f32 %0, %1, %2" : "=v"(d) : "v"(a), "v"(b)); return d;
}
__device__ __forceinline__ f32x2 pk_mul(f32x2 a, f32x2 b){
  f32x2 d; asm("v_pk_mul_f32 %0, %1, %2" : "=v"(d) : "v"(a), "v"(b)); return d;
}
__device__ __forceinline__ f32x2 pk_fma(f32x2 a, f32x2 b, f32x2 c){
  f32x2 d; asm("v_pk_fma_f32 %0, %1, %2, %3" : "=v"(d) : "v"(a), "v"(b), "v"(c)); return d;
}
__device__ __forceinline__ f32x2 up2(uint32_t u){
  f32x2 r; r.x = bflo(u); r.y = bfhiraw(u); return r;
}

// ---------------- rel_enc packing (both tables, one launch, bf16) ----------------
__global__ void k_relpack(const float* __restrict__ relH, const float* __restrict__ relW,
                          uint4* __restrict__ rqkH, uint4* __restrict__ rveH,
                          uint4* __restrict__ rqkW, uint4* __restrict__ rveW) {
  int NJ = blockIdx.x ? 255 : 511;
  const float* rel = blockIdx.x ? relW : relH;
  uint4* rqk = blockIdx.x ? rqkW : rqkH;
  uint4* rve = blockIdx.x ? rveW : rveH;
  int j = threadIdx.x;
  if (j >= NJ) return;
  const float* q = rel;
  const float* k = rel + 4*NJ;
  const float* v = rel + 8*NJ;
  int jr = NJ-1-j;
  uint4 a;
  a.x = pk2(q[0*NJ+j], q[1*NJ+j]);
  a.y = pk2(q[2*NJ+j], q[3*NJ+j]);
  a.z = pk2(k[0*NJ+jr], k[1*NJ+jr]);
  a.w = pk2(k[2*NJ+jr], k[3*NJ+jr]);
  rqk[j] = a;
  uint4 b;
  b.x = pk2(v[0*NJ+j], v[1*NJ+j]);
  b.y = pk2(v[2*NJ+j], v[3*NJ+j]);
  b.z = pk2(v[4*NJ+j], v[5*NJ+j]);
  b.w = pk2(v[6*NJ+j], v[7*NJ+j]);
  rve[j] = b;
}

// ---------------- conv1 + bn + relu : NCHW in -> NHWC out ----------------
__global__ __launch_bounds__(256)
void k_conv1(const float* __restrict__ in, const float* __restrict__ w,
             const float* __restrict__ bn, float* __restrict__ out) {
  __shared__ float L[64*65];
  int tid = threadIdx.x;
  int p0 = blockIdx.x * 64;
  int lane = tid & 63;
  int wvs = __builtin_amdgcn_readfirstlane(tid >> 6);
  #pragma unroll
  for (int rr = 0; rr < 16; ++rr) {
    int c = wvs*16 + rr;
    L[lane*65 + c] = in[(size_t)c*32768 + p0 + lane];
  }
  __syncthreads();
  f32x2 xv2[32];
  #pragma unroll
  for (int c2 = 0; c2 < 32; ++c2) {
    xv2[c2].x = L[lane*65 + 2*c2];
    xv2[c2].y = L[lane*65 + 2*c2 + 1];
  }
  float val[16];
  #pragma unroll
  for (int r = 0; r < 16; ++r) {
    int o = wvs*16 + r;
    const f32x2* wr = (const f32x2*)(w + o*64);
    f32x2 a2 = {0.f, 0.f};
    #pragma unroll
    for (int c2 = 0; c2 < 32; ++c2) a2 = wr[c2]*xv2[c2] + a2;
    float acc = a2.x + a2.y;
    float s = bn[o] * rsqrtf(bn[192+o] + EPSF);
    val[r] = fmaxf(fmaf(acc, s, fmaf(-bn[128+o], s, bn[64+o])), 0.f);
  }
  __syncthreads();
  #pragma unroll
  for (int r = 0; r < 16; ++r) L[lane*65 + wvs*16 + r] = val[r];
  __syncthreads();
  float4* dst = (float4*)(out + (size_t)p0*64);
  #pragma unroll
  for (int k = 0; k < 4; ++k) {
    int f4 = tid + k*256;
    int f = f4*4; int p = f >> 6, o = f & 63;
    float4 v;
    v.x = L[p*65+o]; v.y = L[p*65+o+1]; v.z = L[p*65+o+2]; v.w = L[p*65+o+3];
    dst[f4] = v;
  }
}

// ---------------- kqv projection + bn -> bf16 K/V + f32 Q ----------------
template<int LEN, int RS, int CS>
__global__ __launch_bounds__(512)
void k_kqv(const float* __restrict__ in, const float* __restrict__ w,
           const float* __restrict__ bn, uint4* __restrict__ kvV,
           uint2* __restrict__ kvK, float* __restrict__ qb) {
  __shared__ float L[64*65];
  int tid = threadIdx.x;
  int n = blockIdx.x;
  int y0 = blockIdx.y * 64;
  #pragma unroll
  for (int rr = 0; rr < 8; ++rr) {
    int idx = tid + rr*512;
    int yy = idx >> 6, c = idx & 63;
    L[yy*65 + c] = in[((size_t)(y0+yy)*RS + (size_t)n*CS)*64 + c];
  }
  __syncthreads();
  int hd = __builtin_amdgcn_readfirstlane(tid >> 6);
  int yy = tid & 63;
  f32x2 xv2[32];
  #pragma unroll
  for (int c2 = 0; c2 < 32; ++c2) {
    xv2[c2].x = L[yy*65 + 2*c2];
    xv2[c2].y = L[yy*65 + 2*c2 + 1];
  }
  float val[16];
  #pragma unroll
  for (int r = 0; r < 16; ++r) {
    int o = hd*16 + r;
    const f32x2* wr = (const f32x2*)(w + o*64);
    f32x2 a2 = {0.f, 0.f};
    #pragma unroll
    for (int c2 = 0; c2 < 32; ++c2) a2 = wr[c2]*xv2[c2] + a2;
    float acc = a2.x + a2.y;
    float s = bn[o] * rsqrtf(bn[384+o] + EPSF);
    val[r] = fmaf(acc, s, fmaf(-bn[256+o], s, bn[128+o]));
  }
  size_t base = ((size_t)n*8 + hd)*LEN + (y0 + yy);
  kvK[base] = make_uint2(pk2(val[0],val[1]), pk2(val[2],val[3]));
  kvV[base] = make_uint4(pk2(val[8],val[9]),  pk2(val[10],val[11]),
                         pk2(val[12],val[13]), pk2(val[14],val[15]));
  float4 qq; qq.x = val[4]; qq.y = val[5]; qq.z = val[6]; qq.w = val[7];
  *(float4*)(qb + base*4) = qq;
}

// ---------------- axial attention core (v10: NB n's per block, XB=4 window) ----------------
struct E4 { f32x2 qe0, qe1, ke0, ke1; };   // unpacked qe'/ke'' entry
struct V4 { f32x2 a, b, c, d; };           // unpacked ve entry

__device__ __forceinline__ E4 upQK(uint4 u){
  E4 r; r.qe0 = up2(u.x); r.qe1 = up2(u.y); r.ke0 = up2(u.z); r.ke1 = up2(u.w); return r;
}
__device__ __forceinline__ V4 upVE(uint4 u){
  V4 r; r.a = up2(u.x); r.b = up2(u.y); r.c = up2(u.z); r.d = up2(u.w); return r;
}
// logit2 = kt.(q + ke'') + q.qe'
__device__ __forceinline__ float pairA(f32x2 q01, f32x2 q23, const E4& e,
                                       f32x2 ktlo, f32x2 kthi) {
  f32x2 t0 = pk_add(q01, e.ke0);
  f32x2 t1 = pk_add(q23, e.ke1);
  f32x2 s  = pk_mul(t0, ktlo);
  s = pk_fma(t1, kthi, s);
  s = pk_fma(q01, e.qe0, s);
  s = pk_fma(q23, e.qe1, s);
  return s.x + s.y;
}
__device__ __forceinline__ void pairB(float ex, const V4& ve,
                                      f32x2 va01, f32x2 va23, f32x2 vb01, f32x2 vb23,
                                      f32x2* A, float& ss) {
  ss += ex;
  f32x2 e2; e2.x = ex; e2.y = ex;
  A[0] = pk_fma(e2, pk_add(va01, ve.a), A[0]);
  A[1] = pk_fma(e2, pk_add(va23, ve.b), A[1]);
  A[2] = pk_fma(e2, pk_add(vb01, ve.c), A[2]);
  A[3] = pk_fma(e2, pk_add(vb23, ve.d), A[3]);
}

// Block = (n-block of NB, head). T = NB*(LEN/4)*G threads.
// thread (g, ni, tl): n = n0+ni, x = 4*tl+i, y in [g*YR, (g+1)*YR).
// Tables staged ONCE per block (shared across NB n's).
template<int LEN, int NB, int G, bool RELUO, int XS, int NS>
__global__ __launch_bounds__(NB*(LEN/4)*G, 2)
void k_attn7(const uint4* __restrict__ kvV, const uint2* __restrict__ kvK,
             const float* __restrict__ qb, const uint4* __restrict__ rqk,
             const uint4* __restrict__ rve, const float* __restrict__ lbn,
             float* __restrict__ out) {
  constexpr int NJ = 2*LEN-1;
  constexpr int NJ4 = (NJ+1)/4;
  constexpr int XT = LEN/4;
  constexpr int T = NB*XT*G;
  constexpr int YR = LEN/G;
  constexpr size_t S1 = (size_t)NB*LEN*48 + (size_t)NJ4*4*16*2;
  constexpr size_t S2 = (size_t)(G-1)*NB*LEN*40;
  constexpr size_t PS = S1 > S2 ? S1 : S2;
  int nb = blockIdx.x >> 3;
  int hd = blockIdx.x & 7;
  int n0 = nb * NB;
  int t  = threadIdx.x;

  __shared__ __align__(16) char pool[PS];
  f32x4* sKt = (f32x4*)(pool);                                // [NB*LEN] A0L*k
  f32x4* sVa = (f32x4*)(pool + (size_t)NB*LEN*16);            // [NB*LEN] v0..3
  f32x4* sVb = (f32x4*)(pool + (size_t)NB*LEN*32);            // [NB*LEN] v4..7
  uint4* tQK = (uint4*)(pool + (size_t)NB*LEN*48);            // [4][NJ4]
  uint4* tVE = (uint4*)(pool + (size_t)NB*LEN*48 + (size_t)NJ4*64); // [4][NJ4]

  float A0L, A1L, A2L;
  {
    int c0 = hd, c1 = 8+hd, c2 = 16+hd;
    A0L = lbn[c0]*rsqrtf(lbn[72+c0]+EPSF)*LOG2E;
    A1L = lbn[c1]*rsqrtf(lbn[72+c1]+EPSF)*LOG2E;
    A2L = lbn[c2]*rsqrtf(lbn[72+c2]+EPSF)*LOG2E;
  }
  float A0g = (fabsf(A0L) > 1e-25f) ? A0L : copysignf(1e-25f, A0L);
  float ratio = A2L / A0g;

  // stage K/V for NB sequences
  for (int i = t; i < NB*LEN; i += T) {
    int nn = i / LEN, yy = i % LEN;
    size_t src = ((size_t)(n0+nn)*8 + hd)*LEN + yy;
    uint2 kk = kvK[src];
    uint4 vv = kvV[src];
    f32x4 kt; kt.x=bflo(kk.x)*A0g; kt.y=bfhi(kk.x)*A0g; kt.z=bflo(kk.y)*A0g; kt.w=bfhi(kk.y)*A0g;
    sKt[i] = kt;
    f32x4 va; va.x=bflo(vv.x); va.y=bfhi(vv.x); va.z=bflo(vv.y); va.w=bfhi(vv.y);
    sVa[i] = va;
    f32x4 vb; vb.x=bflo(vv.z); vb.y=bfhi(vv.z); vb.z=bflo(vv.w); vb.w=bfhi(vv.w);
    sVb[i] = vb;
  }
  // stage tables (once per block, shared across NB n's)
  for (int j = t; j < NJ; j += T) {
    uint4 a = rqk[j];
    uint4 sq;
    sq.x = pk2(bflo(a.x)*A1L,   bfhi(a.x)*A1L);
    sq.y = pk2(bflo(a.y)*A1L,   bfhi(a.y)*A1L);
    sq.z = pk2(bflo(a.z)*ratio, bfhi(a.z)*ratio);
    sq.w = pk2(bflo(a.w)*ratio, bfhi(a.w)*ratio);
    int r = j & 3, mm = j >> 2;
    tQK[r*NJ4 + mm] = sq;
    tVE[r*NJ4 + mm] = rve[j];
  }

  int g  = t / (NB*XT);
  int u  = t % (NB*XT);
  int ni = u / XT;
  int tl = u % XT;
  int y0 = g * YR;
  int x0 = 4 * tl;
  int niL = ni * LEN;
  size_t kb = ((size_t)(n0+ni)*8 + hd)*LEN;

  f32x2 q01[4], q23[4];
  #pragma unroll
  for (int i = 0; i < 4; ++i) {
    f32x4 qq = *(const f32x4*)(qb + (kb + x0 + i)*4);
    q01[i].x = qq.x; q01[i].y = qq.y;
    q23[i].x = qq.z; q23[i].y = qq.w;
  }

  float m[4], ss[4];
  f32x2 acc[4][4];
  #pragma unroll
  for (int i=0;i<4;++i){ m[i]=-3.0e38f; ss[i]=0.f;
    #pragma unroll
    for(int d=0;d<4;++d){ acc[i][d].x=0.f; acc[i][d].y=0.f; } }

  __syncthreads();

  // window prologue: (y0 + LEN-1) & 3 == 3 always (y0, x0 mult of 4)
  int mi = ((y0 + LEN-1) >> 2) - (x0 >> 2);
  E4 Wq0 = upQK(tQK[0*NJ4 + mi]), Wq1 = upQK(tQK[1*NJ4 + mi]), Wq2 = upQK(tQK[2*NJ4 + mi]);
  V4 Wv0 = upVE(tVE[0*NJ4 + mi]), Wv1 = upVE(tVE[1*NJ4 + mi]), Wv2 = upVE(tVE[2*NJ4 + mi]);

  for (int cc = 0; cc < YR/4; ++cc) {
    int yb = niL + y0 + 4*cc;
    int ma = mi + cc;
    int mb = ma + 1;
    float lr[4][4];
    // ---- pass A (parities 3,0,1,2) ----
    E4 E3 = upQK(tQK[3*NJ4 + ma]);
    { f32x4 kt = sKt[yb]; f32x2 kl = kt.lo, kh = kt.hi;
      lr[0][0]=pairA(q01[0],q23[0],E3, kl,kh); lr[1][0]=pairA(q01[1],q23[1],Wq2,kl,kh);
      lr[2][0]=pairA(q01[2],q23[2],Wq1,kl,kh); lr[3][0]=pairA(q01[3],q23[3],Wq0,kl,kh); }
    E4 E0 = upQK(tQK[0*NJ4 + mb]);
    { f32x4 kt = sKt[yb+1]; f32x2 kl = kt.lo, kh = kt.hi;
      lr[0][1]=pairA(q01[0],q23[0],E0, kl,kh); lr[1][1]=pairA(q01[1],q23[1],E3, kl,kh);
      lr[2][1]=pairA(q01[2],q23[2],Wq2,kl,kh); lr[3][1]=pairA(q01[3],q23[3],Wq1,kl,kh); }
    E4 E1 = upQK(tQK[1*NJ4 + mb]);
    { f32x4 kt = sKt[yb+2]; f32x2 kl = kt.lo, kh = kt.hi;
      lr[0][2]=pairA(q01[0],q23[0],E1, kl,kh); lr[1][2]=pairA(q01[1],q23[1],E0, kl,kh);
      lr[2][2]=pairA(q01[2],q23[2],E3, kl,kh); lr[3][2]=pairA(q01[3],q23[3],Wq2,kl,kh); }
    E4 E2 = upQK(tQK[2*NJ4 + mb]);
    { f32x4 kt = sKt[yb+3]; f32x2 kl = kt.lo, kh = kt.hi;
      lr[0][3]=pairA(q01[0],q23[0],E2, kl,kh); lr[1][3]=pairA(q01[1],q23[1],E1, kl,kh);
      lr[2][3]=pairA(q01[2],q23[2],E0, kl,kh); lr[3][3]=pairA(q01[3],q23[3],E3, kl,kh); }
    Wq0 = E0; Wq1 = E1; Wq2 = E2;
    // ---- branchless chunk rescale (pk_mul) ----
    #pragma unroll
    for (int i = 0; i < 4; ++i) {
      float cm = fmaxf(fmaxf(lr[i][0], lr[i][1]), fmaxf(lr[i][2], lr[i][3]));
      float mn = fmaxf(m[i], cm);
      float sc = __builtin_amdgcn_exp2f(m[i] - mn);
      m[i] = mn; ss[i] *= sc;
      f32x2 sc2; sc2.x = sc; sc2.y = sc;
      #pragma unroll
      for (int d = 0; d < 4; ++d) acc[i][d] = pk_mul(acc[i][d], sc2);
    }
    // ---- pass B (same window schedule) ----
    V4 F3 = upVE(tVE[3*NJ4 + ma]);
    { f32x4 va = sVa[yb], vb = sVb[yb];
      pairB(__builtin_amdgcn_exp2f(lr[0][0]-m[0]), F3,  va.lo,va.hi,vb.lo,vb.hi, acc[0], ss[0]);
      pairB(__builtin_amdgcn_exp2f(lr[1][0]-m[1]), Wv2, va.lo,va.hi,vb.lo,vb.hi, acc[1], ss[1]);
      pairB(__builtin_amdgcn_exp2f(lr[2][0]-m[2]), Wv1, va.lo,va.hi,vb.lo,vb.hi, acc[2], ss[2]);
      pairB(__builtin_amdgcn_exp2f(lr[3][0]-m[3]), Wv0, va.lo,va.hi,vb.lo,vb.hi, acc[3], ss[3]); }
    V4 F0 = upVE(tVE[0*NJ4 + mb]);
    { f32x4 va = sVa[yb+1], vb = sVb[yb+1];
      pairB(__builtin_amdgcn_exp2f(lr[0][1]-m[0]), F0,  va.lo,va.hi,vb.lo,vb.hi, acc[0], ss[0]);
      pairB(__builtin_amdgcn_exp2f(lr[1][1]-m[1]), F3,  va.lo,va.hi,vb.lo,vb.hi, acc[1], ss[1]);
      pairB(__builtin_amdgcn_exp2f(lr[2][1]-m[2]), Wv2, va.lo,va.hi,vb.lo,vb.hi, acc[2], ss[2]);
      pairB(__builtin_amdgcn_exp2f(lr[3][1]-m[3]), Wv1, va.lo,va.hi,vb.lo,vb.hi, acc[3], ss[3]); }
    V4 F1 = upVE(tVE[1*NJ4 + mb]);
    { f32x4 va = sVa[yb+2], vb = sVb[yb+2];
      pairB(__builtin_amdgcn_exp2f(lr[0][2]-m[0]), F1,  va.lo,va.hi,vb.lo,vb.hi, acc[0], ss[0]);
      pairB(__builtin_amdgcn_exp2f(lr[1][2]-m[1]), F0,  va.lo,va.hi,vb.lo,vb.hi, acc[1], ss[1]);
      pairB(__builtin_amdgcn_exp2f(lr[2][2]-m[2]), F3,  va.lo,va.hi,vb.lo,vb.hi, acc[2], ss[2]);
      pairB(__builtin_amdgcn_exp2f(lr[3][2]-m[3]), Wv2, va.lo,va.hi,vb.lo,vb.hi, acc[3], ss[3]); }
    V4 F2 = upVE(tVE[2*NJ4 + mb]);
    { f32x4 va = sVa[yb+3], vb = sVb[yb+3];
      pairB(__builtin_amdgcn_exp2f(lr[0][3]-m[0]), F2,  va.lo,va.hi,vb.lo,vb.hi, acc[0], ss[0]);
      pairB(__builtin_amdgcn_exp2f(lr[1][3]-m[1]), F1,  va.lo,va.hi,vb.lo,vb.hi, acc[1], ss[1]);
      pairB(__builtin_amdgcn_exp2f(lr[2][3]-m[2]), F0,  va.lo,va.hi,vb.lo,vb.hi, acc[2], ss[2]);
      pairB(__builtin_amdgcn_exp2f(lr[3][3]-m[3]), F3,  va.lo,va.hi,vb.lo,vb.hi, acc[3], ss[3]); }
    Wv0 = F0; Wv1 = F1; Wv2 = F2;
  }

  // ---- one-shot G-way merge via LDS ----
  __syncthreads();
  float4* M0 = (float4*)(pool);
  float4* M1 = (float4*)(pool + (size_t)(G-1)*NB*LEN*16);
  float2* MS = (float2*)(pool + (size_t)(G-1)*NB*LEN*32);
  int xb = niL + x0;
  if (g > 0) {
    #pragma unroll
    for (int i = 0; i < 4; ++i) {
      int slot = (g-1)*NB*LEN + xb + i;
      M0[slot] = make_float4(acc[i][0].x,acc[i][0].y,acc[i][1].x,acc[i][1].y);
      M1[slot] = make_float4(acc[i][2].x,acc[i][2].y,acc[i][3].x,acc[i][3].y);
      MS[slot] = make_float2(m[i], ss[i]);
    }
  }
  __syncthreads();
  if (g == 0) {
    #pragma unroll
    for (int i = 0; i < 4; ++i) {
      float M = m[i];
      float2 oms[G-1];
      #pragma unroll
      for (int gg = 1; gg < G; ++gg) {
        oms[gg-1] = MS[(gg-1)*NB*LEN + xb + i];
        M = fmaxf(M, oms[gg-1].x);
      }
      float w0 = __builtin_amdgcn_exp2f(m[i] - M);
      float st = ss[i]*w0;
      float a[8];
      a[0]=acc[i][0].x*w0; a[1]=acc[i][0].y*w0; a[2]=acc[i][1].x*w0; a[3]=acc[i][1].y*w0;
      a[4]=acc[i][2].x*w0; a[5]=acc[i][2].y*w0; a[6]=acc[i][3].x*w0; a[7]=acc[i][3].y*w0;
      #pragma unroll
      for (int gg = 1; gg < G; ++gg) {
        int slot = (gg-1)*NB*LEN + xb + i;
        float wg = __builtin_amdgcn_exp2f(oms[gg-1].x - M);
        st += oms[gg-1].y*wg;
        float4 a0 = M0[slot];
        float4 a1 = M1[slot];
        a[0] = fmaf(a0.x, wg, a[0]); a[1] = fmaf(a0.y, wg, a[1]);
        a[2] = fmaf(a0.z, wg, a[2]); a[3] = fmaf(a0.w, wg, a[3]);
        a[4] = fmaf(a1.x, wg, a[4]); a[5] = fmaf(a1.y, wg, a[5]);
        a[6] = fmaf(a1.z, wg, a[6]); a[7] = fmaf(a1.w, wg, a[7]);
      }
      float inv = 1.0f / st;
      float* dst = out + ((size_t)(x0+i)*XS + (size_t)(n0+ni)*NS)*64 + hd*8;
      float4 lo, hi;
      lo.x = a[0]*inv; lo.y = a[1]*inv; lo.z = a[2]*inv; lo.w = a[3]*inv;
      hi.x = a[4]*inv; hi.y = a[5]*inv; hi.z = a[6]*inv; hi.w = a[7]*inv;
      if (RELUO) {
        lo.x=fmaxf(lo.x,0.f); lo.y=fmaxf(lo.y,0.f); lo.z=fmaxf(lo.z,0.f); lo.w=fmaxf(lo.w,0.f);
        hi.x=fmaxf(hi.x,0.f); hi.y=fmaxf(hi.y,0.f); hi.z=fmaxf(hi.z,0.f); hi.w=fmaxf(hi.w,0.f);
      }
      *(float4*)dst = lo;
      *((float4*)dst + 1) = hi;
    }
  }
}

// ---------------- conv3 + bn + residual + relu : NHWC in -> NCHW out ----------------
__global__ __launch_bounds__(256)
void k_conv3(const float* __restrict__ in, const float* __restrict__ w,
             const float* __restrict__ bn, const float* __restrict__ resid,
             float* __restrict__ out) {
  __shared__ float L[64*65];
  int tid = threadIdx.x;
  int p0 = blockIdx.x * 64;
  const float4* src = (const float4*)(in + (size_t)p0*64);
  #pragma unroll
  for (int k = 0; k < 4; ++k) {
    int f4 = tid + k*256;
    float4 v = src[f4];
    int f = f4*4; int p = f >> 6, o = f & 63;
    L[p*65+o] = v.x; L[p*65+o+1] = v.y; L[p*65+o+2] = v.z; L[p*65+o+3] = v.w;
  }
  __syncthreads();
  int lane = tid & 63;
  int wvs = __builtin_amdgcn_readfirstlane(tid >> 6);
  f32x2 xv2[32];
  #pragma unroll
  for (int c2 = 0; c2 < 32; ++c2) {
    xv2[c2].x = L[lane*65 + 2*c2];
    xv2[c2].y = L[lane*65 + 2*c2 + 1];
  }
  #pragma unroll
  for (int r = 0; r < 16; ++r) {
    int o = wvs*16 + r;
    const f32x2* wr = (const f32x2*)(w + o*64);
    f32x2 a2 = {0.f, 0.f};
    #pragma unroll
    for (int c2 = 0; c2 < 32; ++c2) a2 = wr[c2]*xv2[c2] + a2;
    float acc = a2.x + a2.y;
    float s = bn[o] * rsqrtf(bn[192+o] + EPSF);
    float val = fmaf(acc, s, fmaf(-bn[128+o], s, bn[64+o]));
    size_t idx = (size_t)o*32768 + p0 + lane;
    out[idx] = fmaxf(val + resid[idx], 0.f);
  }
}

extern "C" void kernel_launch(void* const* d_in, const int* in_sizes, int n_in,
                              void* d_out, int out_size, void* d_ws, size_t ws_size,
                              hipStream_t stream) {
  const float* x         = (const float*)d_in[0];
  const float* conv1_w   = (const float*)d_in[1];
  const float* bn1       = (const float*)d_in[2];
  const float* kqv_w_h   = (const float*)d_in[3];
  const float* kqv_bn_h  = (const float*)d_in[4];
  const float* lbn_h     = (const float*)d_in[5];
  const float* rel_h     = (const float*)d_in[6];
  const float* kqv_w_w   = (const float*)d_in[7];
  const float* kqv_bn_w  = (const float*)d_in[8];
  const float* lbn_w     = (const float*)d_in[9];
  const float* rel_w     = (const float*)d_in[10];
  const float* conv3_w   = (const float*)d_in[11];
  const float* bn3       = (const float*)d_in[12];
  float* outp = (float*)d_out;
  char* ws = (char*)d_ws;

  float* A    = (float*)(ws);                    // 8 MiB
  uint4* kvV  = (uint4*)(ws + 8388608);          // 4 MiB
  uint2* kvK  = (uint2*)(ws + 12582912);         // 2 MiB
  float* qb   = (float*)(ws + 14680064);         // 4 MiB (f32 q)
  uint4* rqkH = (uint4*)(ws + 18874368);
  uint4* rveH = (uint4*)(ws + 18882560);
  uint4* rqkW = (uint4*)(ws + 18890752);
  uint4* rveW = (uint4*)(ws + 18894848);

  k_relpack<<<2, 512, 0, stream>>>(rel_h, rel_w, rqkH, rveH, rqkW, rveW);

  // conv1 + bn1 + relu : x NCHW -> A NHWC
  k_conv1<<<512, 256, 0, stream>>>(x, conv1_w, bn1, A);

  // axial-H: n = w (128), seq = h (256); NB=1, G=4 -> 1024 blocks x 256 thr (r8 config)
  k_kqv<256,128,1><<<dim3(128,4), 512, 0, stream>>>(A, kqv_w_h, kqv_bn_h, kvV, kvK, qb);
  k_attn7<256,1,4,false,128,1><<<1024, 256, 0, stream>>>(kvV, kvK, qb, rqkH, rveH, lbn_h, A);

  // axial-W: n = h (256), seq = w (128); NB=2, G=4 -> 1024 blocks x 256 thr; relu fused
  k_kqv<128,1,128><<<dim3(256,2), 512, 0, stream>>>(A, kqv_w_w, kqv_bn_w, kvV, kvK, qb);
  k_attn7<128,2,4,true,1,128><<<1024, 256, 0, stream>>>(kvV, kvK, qb, rqkW, rveW, lbn_w, A);

  // conv3 + bn3 + residual + relu : A NHWC -> out NCHW
  k_conv3<<<512, 256, 0, stream>>>(A, conv3_w, bn3, x, outp);
}

// Round 11
// 171.700 us; speedup vs baseline: 1.1706x; 1.0329x over previous
//
#include <hip/hip_runtime.h>
#include <stdint.h>

#define EPSF 1e-5f
#define LOG2E 1.4426950408889634f

typedef float f32x2 __attribute__((ext_vector_type(2)));
typedef float f32x4 __attribute__((ext_vector_type(4)));

__device__ __forceinline__ float bflo(uint32_t u){ union{uint32_t u;float f;}c; c.u=u<<16; return c.f; }
__device__ __forceinline__ float bfhi(uint32_t u){ union{uint32_t u;float f;}c; c.u=u&0xffff0000u; return c.f; }
// raw high-half: value == bf16_hi * (1+delta), |delta| <= 2^-7
__device__ __forceinline__ float bfhiraw(uint32_t u){ union{uint32_t u;float f;}c; c.u=u; return c.f; }
__device__ __forceinline__ uint32_t f2bf(float f){ union{float f;uint32_t u;}c; c.f=f; uint32_t u=c.u; return (u + 0x7fffu + ((u>>16)&1u)) >> 16; }
__device__ __forceinline__ uint32_t pk2(float a, float b){ return f2bf(a) | (f2bf(b)<<16); }

// ---- VOP3P packed f32 (gfx950). NOTE: throughput-neutral vs scalar (same FLOP/cyc),
// kept for code density / issue-slot savings only.
__device__ __forceinline__ f32x2 pk_add(f32x2 a, f32x2 b){
  f32x2 d; asm("v_pk_add_f32 %0, %1, %2" : "=v"(d) : "v"(a), "v"(b)); return d;
}
__device__ __forceinline__ f32x2 pk_mul(f32x2 a, f32x2 b){
  f32x2 d; asm("v_pk_mul_f32 %0, %1, %2" : "=v"(d) : "v"(a), "v"(b)); return d;
}
__device__ __forceinline__ f32x2 pk_fma(f32x2 a, f32x2 b, f32x2 c){
  f32x2 d; asm("v_pk_fma_f32 %0, %1, %2, %3" : "=v"(d) : "v"(a), "v"(b), "v"(c)); return d;
}
__device__ __forceinline__ f32x2 up2(uint32_t u){
  f32x2 r; r.x = bflo(u); r.y = bfhiraw(u); return r;
}

// ---------------- conv1 + bn + relu (+ relpack tail blocks) ----------------
// blocks [0,512): conv1 NCHW -> NHWC. blocks 512/513: rel_enc packing (H/W).
__global__ __launch_bounds__(256)
void k_conv1(const float* __restrict__ in, const float* __restrict__ w,
             const float* __restrict__ bn, float* __restrict__ out,
             const float* __restrict__ relH, const float* __restrict__ relW,
             uint4* __restrict__ rqkH, uint4* __restrict__ rveH,
             uint4* __restrict__ rqkW, uint4* __restrict__ rveW) {
  if (blockIdx.x >= 512) {
    int which = blockIdx.x - 512;
    int NJ = which ? 255 : 511;
    const float* rel = which ? relW : relH;
    uint4* rqk = which ? rqkW : rqkH;
    uint4* rve = which ? rveW : rveH;
    const float* q = rel;
    const float* k = rel + 4*NJ;
    const float* v = rel + 8*NJ;
    for (int j = threadIdx.x; j < NJ; j += 256) {
      int jr = NJ-1-j;
      uint4 a;
      a.x = pk2(q[0*NJ+j], q[1*NJ+j]);
      a.y = pk2(q[2*NJ+j], q[3*NJ+j]);
      a.z = pk2(k[0*NJ+jr], k[1*NJ+jr]);
      a.w = pk2(k[2*NJ+jr], k[3*NJ+jr]);
      rqk[j] = a;
      uint4 b;
      b.x = pk2(v[0*NJ+j], v[1*NJ+j]);
      b.y = pk2(v[2*NJ+j], v[3*NJ+j]);
      b.z = pk2(v[4*NJ+j], v[5*NJ+j]);
      b.w = pk2(v[6*NJ+j], v[7*NJ+j]);
      rve[j] = b;
    }
    return;
  }
  __shared__ float L[64*65];
  int tid = threadIdx.x;
  int p0 = blockIdx.x * 64;
  int lane = tid & 63;
  int wvs = __builtin_amdgcn_readfirstlane(tid >> 6);
  #pragma unroll
  for (int rr = 0; rr < 16; ++rr) {
    int c = wvs*16 + rr;
    L[lane*65 + c] = in[(size_t)c*32768 + p0 + lane];
  }
  __syncthreads();
  f32x2 xv2[32];
  #pragma unroll
  for (int c2 = 0; c2 < 32; ++c2) {
    xv2[c2].x = L[lane*65 + 2*c2];
    xv2[c2].y = L[lane*65 + 2*c2 + 1];
  }
  float val[16];
  #pragma unroll
  for (int r = 0; r < 16; ++r) {
    int o = wvs*16 + r;
    const f32x2* wr = (const f32x2*)(w + o*64);
    f32x2 a2 = {0.f, 0.f};
    #pragma unroll
    for (int c2 = 0; c2 < 32; ++c2) a2 = wr[c2]*xv2[c2] + a2;
    float acc = a2.x + a2.y;
    float s = bn[o] * rsqrtf(bn[192+o] + EPSF);
    val[r] = fmaxf(fmaf(acc, s, fmaf(-bn[128+o], s, bn[64+o])), 0.f);
  }
  __syncthreads();
  #pragma unroll
  for (int r = 0; r < 16; ++r) L[lane*65 + wvs*16 + r] = val[r];
  __syncthreads();
  float4* dst = (float4*)(out + (size_t)p0*64);
  #pragma unroll
  for (int k = 0; k < 4; ++k) {
    int f4 = tid + k*256;
    int f = f4*4; int p = f >> 6, o = f & 63;
    float4 v;
    v.x = L[p*65+o]; v.y = L[p*65+o+1]; v.z = L[p*65+o+2]; v.w = L[p*65+o+3];
    dst[f4] = v;
  }
}

// ---------------- kqv projection + bn -> bf16 K/V + f32 Q ----------------
template<int LEN, int RS, int CS>
__global__ __launch_bounds__(512)
void k_kqv(const float* __restrict__ in, const float* __restrict__ w,
           const float* __restrict__ bn, uint4* __restrict__ kvV,
           uint2* __restrict__ kvK, float* __restrict__ qb) {
  __shared__ float L[64*65];
  int tid = threadIdx.x;
  int n = blockIdx.x;
  int y0 = blockIdx.y * 64;
  #pragma unroll
  for (int rr = 0; rr < 8; ++rr) {
    int idx = tid + rr*512;
    int yy = idx >> 6, c = idx & 63;
    L[yy*65 + c] = in[((size_t)(y0+yy)*RS + (size_t)n*CS)*64 + c];
  }
  __syncthreads();
  int hd = __builtin_amdgcn_readfirstlane(tid >> 6);
  int yy = tid & 63;
  f32x2 xv2[32];
  #pragma unroll
  for (int c2 = 0; c2 < 32; ++c2) {
    xv2[c2].x = L[yy*65 + 2*c2];
    xv2[c2].y = L[yy*65 + 2*c2 + 1];
  }
  float val[16];
  #pragma unroll
  for (int r = 0; r < 16; ++r) {
    int o = hd*16 + r;
    const f32x2* wr = (const f32x2*)(w + o*64);
    f32x2 a2 = {0.f, 0.f};
    #pragma unroll
    for (int c2 = 0; c2 < 32; ++c2) a2 = wr[c2]*xv2[c2] + a2;
    float acc = a2.x + a2.y;
    float s = bn[o] * rsqrtf(bn[384+o] + EPSF);
    val[r] = fmaf(acc, s, fmaf(-bn[256+o], s, bn[128+o]));
  }
  size_t base = ((size_t)n*8 + hd)*LEN + (y0 + yy);
  kvK[base] = make_uint2(pk2(val[0],val[1]), pk2(val[2],val[3]));
  kvV[base] = make_uint4(pk2(val[8],val[9]),  pk2(val[10],val[11]),
                         pk2(val[12],val[13]), pk2(val[14],val[15]));
  float4 qq; qq.x = val[4]; qq.y = val[5]; qq.z = val[6]; qq.w = val[7];
  *(float4*)(qb + base*4) = qq;
}

// ---------------- axial attention core (shared device body) ----------------
struct E4 { f32x2 qe0, qe1, ke0, ke1; };   // unpacked qe'/ke'' entry
struct V4 { f32x2 a, b, c, d; };           // unpacked ve entry

__device__ __forceinline__ E4 upQK(uint4 u){
  E4 r; r.qe0 = up2(u.x); r.qe1 = up2(u.y); r.ke0 = up2(u.z); r.ke1 = up2(u.w); return r;
}
__device__ __forceinline__ V4 upVE(uint4 u){
  V4 r; r.a = up2(u.x); r.b = up2(u.y); r.c = up2(u.z); r.d = up2(u.w); return r;
}
// logit2 = kt.(q + ke'') + q.qe'
__device__ __forceinline__ float pairA(f32x2 q01, f32x2 q23, const E4& e,
                                       f32x2 ktlo, f32x2 kthi) {
  f32x2 t0 = pk_add(q01, e.ke0);
  f32x2 t1 = pk_add(q23, e.ke1);
  f32x2 s  = pk_mul(t0, ktlo);
  s = pk_fma(t1, kthi, s);
  s = pk_fma(q01, e.qe0, s);
  s = pk_fma(q23, e.qe1, s);
  return s.x + s.y;
}
__device__ __forceinline__ void pairB(float ex, const V4& ve,
                                      f32x2 va01, f32x2 va23, f32x2 vb01, f32x2 vb23,
                                      f32x2* A, float& ss) {
  ss += ex;
  f32x2 e2; e2.x = ex; e2.y = ex;
  A[0] = pk_fma(e2, pk_add(va01, ve.a), A[0]);
  A[1] = pk_fma(e2, pk_add(va23, ve.b), A[1]);
  A[2] = pk_fma(e2, pk_add(vb01, ve.c), A[2]);
  A[3] = pk_fma(e2, pk_add(vb23, ve.d), A[3]);
}

// Block = (n-block of NB, head). T = NB*(LEN/4)*G threads.
template<int LEN, int NB, int G, bool RELUO, int XS, int NS>
__device__ __forceinline__
void attn_body(const uint4* __restrict__ kvV, const uint2* __restrict__ kvK,
               const float* __restrict__ qb, const uint4* __restrict__ rqk,
               const uint4* __restrict__ rve, const float* __restrict__ lbn,
               float* __restrict__ out) {
  constexpr int NJ = 2*LEN-1;
  constexpr int NJ4 = (NJ+1)/4;
  constexpr int XT = LEN/4;
  constexpr int T = NB*XT*G;
  constexpr int YR = LEN/G;
  constexpr size_t S1 = (size_t)NB*LEN*48 + (size_t)NJ4*4*16*2;
  constexpr size_t S2 = (size_t)(G-1)*NB*LEN*40;
  constexpr size_t PS = S1 > S2 ? S1 : S2;
  int nb = blockIdx.x >> 3;
  int hd = blockIdx.x & 7;
  int n0 = nb * NB;
  int t  = threadIdx.x;

  __shared__ __align__(16) char pool[PS];
  f32x4* sKt = (f32x4*)(pool);                                // [NB*LEN] A0L*k
  f32x4* sVa = (f32x4*)(pool + (size_t)NB*LEN*16);            // [NB*LEN] v0..3
  f32x4* sVb = (f32x4*)(pool + (size_t)NB*LEN*32);            // [NB*LEN] v4..7
  uint4* tQK = (uint4*)(pool + (size_t)NB*LEN*48);            // [4][NJ4]
  uint4* tVE = (uint4*)(pool + (size_t)NB*LEN*48 + (size_t)NJ4*64); // [4][NJ4]

  float A0L, A1L, A2L;
  {
    int c0 = hd, c1 = 8+hd, c2 = 16+hd;
    A0L = lbn[c0]*rsqrtf(lbn[72+c0]+EPSF)*LOG2E;
    A1L = lbn[c1]*rsqrtf(lbn[72+c1]+EPSF)*LOG2E;
    A2L = lbn[c2]*rsqrtf(lbn[72+c2]+EPSF)*LOG2E;
  }
  float A0g = (fabsf(A0L) > 1e-25f) ? A0L : copysignf(1e-25f, A0L);
  float ratio = A2L / A0g;

  for (int i = t; i < NB*LEN; i += T) {
    int nn = i / LEN, yy = i % LEN;
    size_t src = ((size_t)(n0+nn)*8 + hd)*LEN + yy;
    uint2 kk = kvK[src];
    uint4 vv = kvV[src];
    f32x4 kt; kt.x=bflo(kk.x)*A0g; kt.y=bfhi(kk.x)*A0g; kt.z=bflo(kk.y)*A0g; kt.w=bfhi(kk.y)*A0g;
    sKt[i] = kt;
    f32x4 va; va.x=bflo(vv.x); va.y=bfhi(vv.x); va.z=bflo(vv.y); va.w=bfhi(vv.y);
    sVa[i] = va;
    f32x4 vb; vb.x=bflo(vv.z); vb.y=bfhi(vv.z); vb.z=bflo(vv.w); vb.w=bfhi(vv.w);
    sVb[i] = vb;
  }
  for (int j = t; j < NJ; j += T) {
    uint4 a = rqk[j];
    uint4 sq;
    sq.x = pk2(bflo(a.x)*A1L,   bfhi(a.x)*A1L);
    sq.y = pk2(bflo(a.y)*A1L,   bfhi(a.y)*A1L);
    sq.z = pk2(bflo(a.z)*ratio, bfhi(a.z)*ratio);
    sq.w = pk2(bflo(a.w)*ratio, bfhi(a.w)*ratio);
    int r = j & 3, mm = j >> 2;
    tQK[r*NJ4 + mm] = sq;
    tVE[r*NJ4 + mm] = rve[j];
  }

  int g  = t / (NB*XT);
  int u  = t % (NB*XT);
  int ni = u / XT;
  int tl = u % XT;
  int y0 = g * YR;
  int x0 = 4 * tl;
  int niL = ni * LEN;
  size_t kb = ((size_t)(n0+ni)*8 + hd)*LEN;

  f32x2 q01[4], q23[4];
  #pragma unroll
  for (int i = 0; i < 4; ++i) {
    f32x4 qq = *(const f32x4*)(qb + (kb + x0 + i)*4);
    q01[i].x = qq.x; q01[i].y = qq.y;
    q23[i].x = qq.z; q23[i].y = qq.w;
  }

  float m[4], ss[4];
  f32x2 acc[4][4];
  #pragma unroll
  for (int i=0;i<4;++i){ m[i]=-3.0e38f; ss[i]=0.f;
    #pragma unroll
    for(int d=0;d<4;++d){ acc[i][d].x=0.f; acc[i][d].y=0.f; } }

  __syncthreads();

  // window prologue: (y0 + LEN-1) & 3 == 3 always (y0, x0 mult of 4)
  int mi = ((y0 + LEN-1) >> 2) - (x0 >> 2);
  E4 Wq0 = upQK(tQK[0*NJ4 + mi]), Wq1 = upQK(tQK[1*NJ4 + mi]), Wq2 = upQK(tQK[2*NJ4 + mi]);
  V4 Wv0 = upVE(tVE[0*NJ4 + mi]), Wv1 = upVE(tVE[1*NJ4 + mi]), Wv2 = upVE(tVE[2*NJ4 + mi]);

  for (int cc = 0; cc < YR/4; ++cc) {
    int yb = niL + y0 + 4*cc;
    int ma = mi + cc;
    int mb = ma + 1;
    float lr[4][4];
    // ---- pass A (parities 3,0,1,2) ----
    E4 E3 = upQK(tQK[3*NJ4 + ma]);
    { f32x4 kt = sKt[yb]; f32x2 kl = kt.lo, kh = kt.hi;
      lr[0][0]=pairA(q01[0],q23[0],E3, kl,kh); lr[1][0]=pairA(q01[1],q23[1],Wq2,kl,kh);
      lr[2][0]=pairA(q01[2],q23[2],Wq1,kl,kh); lr[3][0]=pairA(q01[3],q23[3],Wq0,kl,kh); }
    E4 E0 = upQK(tQK[0*NJ4 + mb]);
    { f32x4 kt = sKt[yb+1]; f32x2 kl = kt.lo, kh = kt.hi;
      lr[0][1]=pairA(q01[0],q23[0],E0, kl,kh); lr[1][1]=pairA(q01[1],q23[1],E3, kl,kh);
      lr[2][1]=pairA(q01[2],q23[2],Wq2,kl,kh); lr[3][1]=pairA(q01[3],q23[3],Wq1,kl,kh); }
    E4 E1 = upQK(tQK[1*NJ4 + mb]);
    { f32x4 kt = sKt[yb+2]; f32x2 kl = kt.lo, kh = kt.hi;
      lr[0][2]=pairA(q01[0],q23[0],E1, kl,kh); lr[1][2]=pairA(q01[1],q23[1],E0, kl,kh);
      lr[2][2]=pairA(q01[2],q23[2],E3, kl,kh); lr[3][2]=pairA(q01[3],q23[3],Wq2,kl,kh); }
    E4 E2 = upQK(tQK[2*NJ4 + mb]);
    { f32x4 kt = sKt[yb+3]; f32x2 kl = kt.lo, kh = kt.hi;
      lr[0][3]=pairA(q01[0],q23[0],E2, kl,kh); lr[1][3]=pairA(q01[1],q23[1],E1, kl,kh);
      lr[2][3]=pairA(q01[2],q23[2],E0, kl,kh); lr[3][3]=pairA(q01[3],q23[3],E3, kl,kh); }
    Wq0 = E0; Wq1 = E1; Wq2 = E2;
    // ---- chunk rescale, skipped when no lane's max grew (exact: skipped == *1.0) ----
    float cm[4];
    bool need = false;
    #pragma unroll
    for (int i = 0; i < 4; ++i) {
      cm[i] = fmaxf(fmaxf(lr[i][0], lr[i][1]), fmaxf(lr[i][2], lr[i][3]));
      need = need || (cm[i] > m[i]);
    }
    if (__any(need)) {
      #pragma unroll
      for (int i = 0; i < 4; ++i) {
        float mn = fmaxf(m[i], cm[i]);
        float sc = __builtin_amdgcn_exp2f(m[i] - mn);
        m[i] = mn; ss[i] *= sc;
        f32x2 sc2; sc2.x = sc; sc2.y = sc;
        #pragma unroll
        for (int d = 0; d < 4; ++d) acc[i][d] = pk_mul(acc[i][d], sc2);
      }
    }
    // ---- pass B (same window schedule) ----
    V4 F3 = upVE(tVE[3*NJ4 + ma]);
    { f32x4 va = sVa[yb], vb = sVb[yb];
      pairB(__builtin_amdgcn_exp2f(lr[0][0]-m[0]), F3,  va.lo,va.hi,vb.lo,vb.hi, acc[0], ss[0]);
      pairB(__builtin_amdgcn_exp2f(lr[1][0]-m[1]), Wv2, va.lo,va.hi,vb.lo,vb.hi, acc[1], ss[1]);
      pairB(__builtin_amdgcn_exp2f(lr[2][0]-m[2]), Wv1, va.lo,va.hi,vb.lo,vb.hi, acc[2], ss[2]);
      pairB(__builtin_amdgcn_exp2f(lr[3][0]-m[3]), Wv0, va.lo,va.hi,vb.lo,vb.hi, acc[3], ss[3]); }
    V4 F0 = upVE(tVE[0*NJ4 + mb]);
    { f32x4 va = sVa[yb+1], vb = sVb[yb+1];
      pairB(__builtin_amdgcn_exp2f(lr[0][1]-m[0]), F0,  va.lo,va.hi,vb.lo,vb.hi, acc[0], ss[0]);
      pairB(__builtin_amdgcn_exp2f(lr[1][1]-m[1]), F3,  va.lo,va.hi,vb.lo,vb.hi, acc[1], ss[1]);
      pairB(__builtin_amdgcn_exp2f(lr[2][1]-m[2]), Wv2, va.lo,va.hi,vb.lo,vb.hi, acc[2], ss[2]);
      pairB(__builtin_amdgcn_exp2f(lr[3][1]-m[3]), Wv1, va.lo,va.hi,vb.lo,vb.hi, acc[3], ss[3]); }
    V4 F1 = upVE(tVE[1*NJ4 + mb]);
    { f32x4 va = sVa[yb+2], vb = sVb[yb+2];
      pairB(__builtin_amdgcn_exp2f(lr[0][2]-m[0]), F1,  va.lo,va.hi,vb.lo,vb.hi, acc[0], ss[0]);
      pairB(__builtin_amdgcn_exp2f(lr[1][2]-m[1]), F0,  va.lo,va.hi,vb.lo,vb.hi, acc[1], ss[1]);
      pairB(__builtin_amdgcn_exp2f(lr[2][2]-m[2]), F3,  va.lo,va.hi,vb.lo,vb.hi, acc[2], ss[2]);
      pairB(__builtin_amdgcn_exp2f(lr[3][2]-m[3]), Wv2, va.lo,va.hi,vb.lo,vb.hi, acc[3], ss[3]); }
    V4 F2 = upVE(tVE[2*NJ4 + mb]);
    { f32x4 va = sVa[yb+3], vb = sVb[yb+3];
      pairB(__builtin_amdgcn_exp2f(lr[0][3]-m[0]), F2,  va.lo,va.hi,vb.lo,vb.hi, acc[0], ss[0]);
      pairB(__builtin_amdgcn_exp2f(lr[1][3]-m[1]), F1,  va.lo,va.hi,vb.lo,vb.hi, acc[1], ss[1]);
      pairB(__builtin_amdgcn_exp2f(lr[2][3]-m[2]), F0,  va.lo,va.hi,vb.lo,vb.hi, acc[2], ss[2]);
      pairB(__builtin_amdgcn_exp2f(lr[3][3]-m[3]), F3,  va.lo,va.hi,vb.lo,vb.hi, acc[3], ss[3]); }
    Wv0 = F0; Wv1 = F1; Wv2 = F2;
  }

  // ---- one-shot G-way merge via LDS ----
  __syncthreads();
  float4* M0 = (float4*)(pool);
  float4* M1 = (float4*)(pool + (size_t)(G-1)*NB*LEN*16);
  float2* MS = (float2*)(pool + (size_t)(G-1)*NB*LEN*32);
  int xb = niL + x0;
  if (g > 0) {
    #pragma unroll
    for (int i = 0; i < 4; ++i) {
      int slot = (g-1)*NB*LEN + xb + i;
      M0[slot] = make_float4(acc[i][0].x,acc[i][0].y,acc[i][1].x,acc[i][1].y);
      M1[slot] = make_float4(acc[i][2].x,acc[i][2].y,acc[i][3].x,acc[i][3].y);
      MS[slot] = make_float2(m[i], ss[i]);
    }
  }
  __syncthreads();
  if (g == 0) {
    #pragma unroll
    for (int i = 0; i < 4; ++i) {
      float M = m[i];
      float2 oms[G-1];
      #pragma unroll
      for (int gg = 1; gg < G; ++gg) {
        oms[gg-1] = MS[(gg-1)*NB*LEN + xb + i];
        M = fmaxf(M, oms[gg-1].x);
      }
      float w0 = __builtin_amdgcn_exp2f(m[i] - M);
      float st = ss[i]*w0;
      float a[8];
      a[0]=acc[i][0].x*w0; a[1]=acc[i][0].y*w0; a[2]=acc[i][1].x*w0; a[3]=acc[i][1].y*w0;
      a[4]=acc[i][2].x*w0; a[5]=acc[i][2].y*w0; a[6]=acc[i][3].x*w0; a[7]=acc[i][3].y*w0;
      #pragma unroll
      for (int gg = 1; gg < G; ++gg) {
        int slot = (gg-1)*NB*LEN + xb + i;
        float wg = __builtin_amdgcn_exp2f(oms[gg-1].x - M);
        st += oms[gg-1].y*wg;
        float4 a0 = M0[slot];
        float4 a1 = M1[slot];
        a[0] = fmaf(a0.x, wg, a[0]); a[1] = fmaf(a0.y, wg, a[1]);
        a[2] = fmaf(a0.z, wg, a[2]); a[3] = fmaf(a0.w, wg, a[3]);
        a[4] = fmaf(a1.x, wg, a[4]); a[5] = fmaf(a1.y, wg, a[5]);
        a[6] = fmaf(a1.z, wg, a[6]); a[7] = fmaf(a1.w, wg, a[7]);
      }
      float inv = 1.0f / st;
      float* dst = out + ((size_t)(x0+i)*XS + (size_t)(n0+ni)*NS)*64 + hd*8;
      float4 lo, hi;
      lo.x = a[0]*inv; lo.y = a[1]*inv; lo.z = a[2]*inv; lo.w = a[3]*inv;
      hi.x = a[4]*inv; hi.y = a[5]*inv; hi.z = a[6]*inv; hi.w = a[7]*inv;
      if (RELUO) {
        lo.x=fmaxf(lo.x,0.f); lo.y=fmaxf(lo.y,0.f); lo.z=fmaxf(lo.z,0.f); lo.w=fmaxf(lo.w,0.f);
        hi.x=fmaxf(hi.x,0.f); hi.y=fmaxf(hi.y,0.f); hi.z=fmaxf(hi.z,0.f); hi.w=fmaxf(hi.w,0.f);
      }
      *(float4*)dst = lo;
      *((float4*)dst + 1) = hi;
    }
  }
}

// Distinct names so rocprof attributes H vs W separately.
__global__ __launch_bounds__(256, 2)
void k_attnH(const uint4* __restrict__ kvV, const uint2* __restrict__ kvK,
             const float* __restrict__ qb, const uint4* __restrict__ rqk,
             const uint4* __restrict__ rve, const float* __restrict__ lbn,
             float* __restrict__ out) {
  attn_body<256,1,4,false,128,1>(kvV, kvK, qb, rqk, rve, lbn, out);
}
__global__ __launch_bounds__(256, 2)
void k_attnW(const uint4* __restrict__ kvV, const uint2* __restrict__ kvK,
             const float* __restrict__ qb, const uint4* __restrict__ rqk,
             const uint4* __restrict__ rve, const float* __restrict__ lbn,
             float* __restrict__ out) {
  attn_body<128,2,4,true,1,128>(kvV, kvK, qb, rqk, rve, lbn, out);
}

// ---------------- conv3 + bn + residual + relu : NHWC in -> NCHW out ----------------
__global__ __launch_bounds__(256)
void k_conv3(const float* __restrict__ in, const float* __restrict__ w,
             const float* __restrict__ bn, const float* __restrict__ resid,
             float* __restrict__ out) {
  __shared__ float L[64*65];
  int tid = threadIdx.x;
  int p0 = blockIdx.x * 64;
  const float4* src = (const float4*)(in + (size_t)p0*64);
  #pragma unroll
  for (int k = 0; k < 4; ++k) {
    int f4 = tid + k*256;
    float4 v = src[f4];
    int f = f4*4; int p = f >> 6, o = f & 63;
    L[p*65+o] = v.x; L[p*65+o+1] = v.y; L[p*65+o+2] = v.z; L[p*65+o+3] = v.w;
  }
  __syncthreads();
  int lane = tid & 63;
  int wvs = __builtin_amdgcn_readfirstlane(tid >> 6);
  f32x2 xv2[32];
  #pragma unroll
  for (int c2 = 0; c2 < 32; ++c2) {
    xv2[c2].x = L[lane*65 + 2*c2];
    xv2[c2].y = L[lane*65 + 2*c2 + 1];
  }
  #pragma unroll
  for (int r = 0; r < 16; ++r) {
    int o = wvs*16 + r;
    const f32x2* wr = (const f32x2*)(w + o*64);
    f32x2 a2 = {0.f, 0.f};
    #pragma unroll
    for (int c2 = 0; c2 < 32; ++c2) a2 = wr[c2]*xv2[c2] + a2;
    float acc = a2.x + a2.y;
    float s = bn[o] * rsqrtf(bn[192+o] + EPSF);
    float val = fmaf(acc, s, fmaf(-bn[128+o], s, bn[64+o]));
    size_t idx = (size_t)o*32768 + p0 + lane;
    out[idx] = fmaxf(val + resid[idx], 0.f);
  }
}

extern "C" void kernel_launch(void* const* d_in, const int* in_sizes, int n_in,
                              void* d_out, int out_size, void* d_ws, size_t ws_size,
                              hipStream_t stream) {
  const float* x         = (const float*)d_in[0];
  const float* conv1_w   = (const float*)d_in[1];
  const float* bn1       = (const float*)d_in[2];
  const float* kqv_w_h   = (const float*)d_in[3];
  const float* kqv_bn_h  = (const float*)d_in[4];
  const float* lbn_h     = (const float*)d_in[5];
  const float* rel_h     = (const float*)d_in[6];
  const float* kqv_w_w   = (const float*)d_in[7];
  const float* kqv_bn_w  = (const float*)d_in[8];
  const float* lbn_w     = (const float*)d_in[9];
  const float* rel_w     = (const float*)d_in[10];
  const float* conv3_w   = (const float*)d_in[11];
  const float* bn3       = (const float*)d_in[12];
  float* outp = (float*)d_out;
  char* ws = (char*)d_ws;

  float* A    = (float*)(ws);                    // 8 MiB
  uint4* kvV  = (uint4*)(ws + 8388608);          // 4 MiB
  uint2* kvK  = (uint2*)(ws + 12582912);         // 2 MiB
  float* qb   = (float*)(ws + 14680064);         // 4 MiB (f32 q)
  uint4* rqkH = (uint4*)(ws + 18874368);
  uint4* rveH = (uint4*)(ws + 18882560);
  uint4* rqkW = (uint4*)(ws + 18890752);
  uint4* rveW = (uint4*)(ws + 18894848);

  // conv1 + bn1 + relu (blocks 0..511) and rel_enc packing (blocks 512,513)
  k_conv1<<<514, 256, 0, stream>>>(x, conv1_w, bn1, A,
                                   rel_h, rel_w, rqkH, rveH, rqkW, rveW);

  // axial-H: n = w (128), seq = h (256)
  k_kqv<256,128,1><<<dim3(128,4), 512, 0, stream>>>(A, kqv_w_h, kqv_bn_h, kvV, kvK, qb);
  k_attnH<<<1024, 256, 0, stream>>>(kvV, kvK, qb, rqkH, rveH, lbn_h, A);

  // axial-W: n = h (256), seq = w (128); relu fused
  k_kqv<128,1,128><<<dim3(256,2), 512, 0, stream>>>(A, kqv_w_w, kqv_bn_w, kvV, kvK, qb);
  k_attnW<<<1024, 256, 0, stream>>>(kvV, kvK, qb, rqkW, rveW, lbn_w, A);

  // conv3 + bn3 + residual + relu : A NHWC -> out NCHW
  k_conv3<<<512, 256, 0, stream>>>(A, conv3_w, bn3, x, outp);
}